// Round 1
// baseline (3760.622 us; speedup 1.0000x reference)
//
#include <hip/hip_runtime.h>
#include <math.h>

#define N_HEADS 4
#define N_NODES 10000
#define EMB 128
#define N_BATCH 4096
#define NQ (2 * N_BATCH) /* 8192 queries: [src(4096), dst(4096)] */
#define K 8
#define TQ 64
#define TN 64

// ---------------------------------------------------------------------------
// Kernel P: per-node squared norms y2[h][n] = sum_d E[h][n][d]^2
// One wave per (h,n). 40000 waves / 4 per block = 10000 blocks.
// ---------------------------------------------------------------------------
__global__ __launch_bounds__(256) void y2_kernel(const float* __restrict__ E,
                                                 float* __restrict__ y2) {
  int wid = (blockIdx.x * 256 + threadIdx.x) >> 6;
  int lane = threadIdx.x & 63;
  if (wid >= N_HEADS * N_NODES) return;
  const float* v = E + (size_t)wid * EMB;
  float2 p = *(const float2*)(v + 2 * lane);
  float s = p.x * p.x + p.y * p.y;
  #pragma unroll
  for (int o = 32; o > 0; o >>= 1) s += __shfl_xor(s, o);
  if (lane == 0) y2[wid] = s;
}

// ---------------------------------------------------------------------------
// Kernel A: fused distance + top-8 (excluding self) per (head, query).
// Rank by score = y2[n] - 2*dot(q,n)  (monotone in d2; x2 per-query const).
// Grid: (NQ/TQ = 128, N_HEADS). Block 256 = 16 q-groups x 16 n-groups, each
// thread owns a 4x4 register tile. LDS: 64x128 query tile + 64x128 node tile,
// both stored with a per-4-row column rotation so compute-phase ds_read_b128
// is conflict-free (q reads) / 2-way (n reads, free per m136).
// ---------------------------------------------------------------------------
__global__ __launch_bounds__(256) void knn_kernel(const float* __restrict__ E,
                                                  const float* __restrict__ y2,
                                                  const int* __restrict__ be,
                                                  int* __restrict__ samples) {
  __shared__ union {
    struct { float qt[TQ][EMB]; float nt[TN][EMB]; } a;   // 65536 B
    struct { float cs[32][132]; int ci[32][132]; } m;     // 33792 B (aliases qt)
  } sm;

  const int h = blockIdx.y;
  const int tile = blockIdx.x;
  const int tid = threadIdx.x;
  const float* Eh = E + (size_t)h * N_NODES * EMB;
  const float* y2h = y2 + h * N_NODES;

  const int tq = tid >> 4;      // 0..15
  const int tn = tid & 15;      // 0..15
  const int q0 = tq * 4;
  const int n0 = tn * 4;

  int myq[4];
  #pragma unroll
  for (int i = 0; i < 4; ++i) myq[i] = be[tile * TQ + q0 + i];

  // stage query tile (swizzled: column c4 stored at (c4 + (row>>2)) & 31)
  for (int idx = tid; idx < TQ * (EMB / 4); idx += 256) {
    int r = idx >> 5, c4 = idx & 31;
    int qn = be[tile * TQ + r];
    float4 v = *(const float4*)(Eh + (size_t)qn * EMB + c4 * 4);
    int c4s = (c4 + ((r >> 2) & 7)) & 31;
    *(float4*)&sm.a.qt[r][c4s * 4] = v;
  }

  float bs[4][K];
  int bi[4][K];
  #pragma unroll
  for (int i = 0; i < 4; ++i)
    #pragma unroll
    for (int k2 = 0; k2 < K; ++k2) { bs[i][k2] = 3.4e38f; bi[i][k2] = 0x7fffffff; }

  const int rq = tq & 7;
  const int rn = tn & 7;

  for (int nb = 0; nb < N_NODES; nb += TN) {
    __syncthreads();
    // stage node tile (same swizzle); OOB rows -> zeros
    for (int idx = tid; idx < TN * (EMB / 4); idx += 256) {
      int r = idx >> 5, c4 = idx & 31;
      int node = nb + r;
      float4 v = make_float4(0.f, 0.f, 0.f, 0.f);
      if (node < N_NODES) v = *(const float4*)(Eh + (size_t)node * EMB + c4 * 4);
      int c4s = (c4 + ((r >> 2) & 7)) & 31;
      *(float4*)&sm.a.nt[r][c4s * 4] = v;
    }
    __syncthreads();

    float acc[4][4] = {{0.f, 0.f, 0.f, 0.f}, {0.f, 0.f, 0.f, 0.f},
                       {0.f, 0.f, 0.f, 0.f}, {0.f, 0.f, 0.f, 0.f}};
    #pragma unroll 4
    for (int dc = 0; dc < 32; ++dc) {
      int qc = ((dc + rq) & 31) * 4;
      int nc = ((dc + rn) & 31) * 4;
      float4 qv[4], nv[4];
      #pragma unroll
      for (int i = 0; i < 4; ++i) qv[i] = *(float4*)&sm.a.qt[q0 + i][qc];
      #pragma unroll
      for (int j = 0; j < 4; ++j) nv[j] = *(float4*)&sm.a.nt[n0 + j][nc];
      #pragma unroll
      for (int i = 0; i < 4; ++i)
        #pragma unroll
        for (int j = 0; j < 4; ++j)
          acc[i][j] += qv[i].x * nv[j].x + qv[i].y * nv[j].y +
                       qv[i].z * nv[j].z + qv[i].w * nv[j].w;
    }

    // selection: insert (score, node) into per-(thread,query) sorted top-8
    float ny[4];
    #pragma unroll
    for (int j = 0; j < 4; ++j) {
      int node = nb + n0 + j;
      ny[j] = (node < N_NODES) ? y2h[node] : 3.0e38f;
    }
    #pragma unroll
    for (int j = 0; j < 4; ++j) {
      int node = nb + n0 + j;
      if (node >= N_NODES) continue;
      #pragma unroll
      for (int i = 0; i < 4; ++i) {
        float s = ny[j] - 2.0f * acc[i][j];
        if (node == myq[i]) continue;  // exclude self (== dropped idx[...,0])
        if (s < bs[i][K - 1] || (s == bs[i][K - 1] && node < bi[i][K - 1])) {
          #pragma unroll
          for (int k2 = K - 1; k2 >= 0; --k2) {
            bool better = (s < bs[i][k2]) || (s == bs[i][k2] && node < bi[i][k2]);
            if (!better) break;
            if (k2 < K - 1) { bs[i][k2 + 1] = bs[i][k2]; bi[i][k2 + 1] = bi[i][k2]; }
            bs[i][k2] = s; bi[i][k2] = node;
          }
        }
      }
    }
  }

  // merge the 16 per-thread lists per query (two halves of 32 queries)
  for (int half = 0; half < 2; ++half) {
    __syncthreads();
    #pragma unroll
    for (int i = 0; i < 4; ++i) {
      int q = q0 + i;
      if ((q >> 5) == half) {
        int qr = q & 31;
        #pragma unroll
        for (int k2 = 0; k2 < K; ++k2) {
          sm.m.cs[qr][tn * K + k2] = bs[i][k2];
          sm.m.ci[qr][tn * K + k2] = bi[i][k2];
        }
      }
    }
    __syncthreads();
    if (tid < 32) {
      float fs2[K]; int fi2[K];
      #pragma unroll
      for (int k2 = 0; k2 < K; ++k2) { fs2[k2] = 3.4e38f; fi2[k2] = 0x7fffffff; }
      for (int c = 0; c < 16 * K; ++c) {
        float s = sm.m.cs[tid][c];
        int idx = sm.m.ci[tid][c];
        if (s < fs2[K - 1] || (s == fs2[K - 1] && idx < fi2[K - 1])) {
          #pragma unroll
          for (int k2 = K - 1; k2 >= 0; --k2) {
            bool better = (s < fs2[k2]) || (s == fs2[k2] && idx < fi2[k2]);
            if (!better) break;
            if (k2 < K - 1) { fs2[k2 + 1] = fs2[k2]; fi2[k2 + 1] = fi2[k2]; }
            fs2[k2] = s; fi2[k2] = idx;
          }
        }
      }
      int gq = tile * TQ + half * 32 + tid;
      #pragma unroll
      for (int k2 = 0; k2 < K; ++k2)
        samples[((size_t)h * NQ + gq) * K + k2] = fi2[k2];
    }
  }
}

// ---------------------------------------------------------------------------
// Kernel B: epilogue. One block per edge b; wave w = head w.
// 16 neighbors (8 src-side + 8 tgt-side) + 8 sentinels (logit 0, dist 1).
// ---------------------------------------------------------------------------
__global__ __launch_bounds__(256) void predict_kernel(
    const float* __restrict__ E, const float* __restrict__ F,
    const float* __restrict__ unc, const float* __restrict__ adj,
    const int* __restrict__ be, const int* __restrict__ samples,
    float* __restrict__ out) {
  int b = blockIdx.x;
  int h = threadIdx.x >> 6;
  int lane = threadIdx.x & 63;
  __shared__ float smv[N_HEADS];

  int srcb = be[b];
  int dstb = be[N_BATCH + b];
  const float* Eh = E + (size_t)h * N_NODES * EMB;
  const float* Fh = F + (size_t)h * N_NODES * EMB;
  float2 es = *(const float2*)(Eh + (size_t)srcb * EMB + 2 * lane);
  float2 ed = *(const float2*)(Eh + (size_t)dstb * EMB + 2 * lane);
  float2 fs = *(const float2*)(Fh + (size_t)srcb * EMB + 2 * lane);
  float2 fd = *(const float2*)(Fh + (size_t)dstb * EMB + 2 * lane);
  float u = unc[0];

  float logit[16], dist[16];
  #pragma unroll
  for (int j = 0; j < 16; ++j) {
    bool isrc = (j < 8);
    int qrow = isrc ? b : (N_BATCH + b);
    int s = samples[((size_t)h * NQ + qrow) * K + (j & 7)];
    float2 ev = *(const float2*)(Eh + (size_t)s * EMB + 2 * lane);
    float2 bb = isrc ? es : ed;
    float2 g = isrc ? fd : fs;
    float dx = bb.x - ev.x, dy = bb.y - ev.y;
    float dot = dx * g.x + dy * g.y;
    float nrm = dx * dx + dy * dy;
    #pragma unroll
    for (int o = 32; o > 0; o >>= 1) {
      dot += __shfl_xor(dot, o);
      nrm += __shfl_xor(nrm, o);
    }
    float a = isrc ? adj[(size_t)s * N_NODES + dstb]
                   : adj[(size_t)srcb * N_NODES + s];
    logit[j] = dot + u * (2.0f * a - 1.0f);
    dist[j] = sqrtf(nrm);
  }

  float m = 0.0f;  // sentinel: 1 - 1.0 = 0
  #pragma unroll
  for (int j = 0; j < 16; ++j) m = fmaxf(m, 1.0f - dist[j]);
  float Z = 8.0f * expf(-m);  // 8 sentinels
  float num = 0.0f;
  #pragma unroll
  for (int j = 0; j < 16; ++j) {
    float e = expf(1.0f - dist[j] - m);
    Z += e;
    num += logit[j] * e;
  }
  if (lane == 0) smv[h] = num / Z;
  __syncthreads();
  if (threadIdx.x == 0) {
    float t = 0.25f * (smv[0] + smv[1] + smv[2] + smv[3]);
    out[b] = 1.0f / (1.0f + expf(-t));
  }
}

// ---------------------------------------------------------------------------
extern "C" void kernel_launch(void* const* d_in, const int* in_sizes, int n_in,
                              void* d_out, int out_size, void* d_ws,
                              size_t ws_size, hipStream_t stream) {
  const float* E = (const float*)d_in[0];    // embeds  (4,10000,128) f32
  const float* F = (const float*)d_in[1];    // field   (4,10000,128) f32
  const float* U = (const float*)d_in[2];    // uncertainty (1) f32
  const float* A = (const float*)d_in[3];    // adj (10000,10000) f32
  const int* be = (const int*)d_in[4];       // batch_edges (2,4096) i32
  float* out = (float*)d_out;                // (4096,) f32

  // workspace layout: y2 (4*10000 f32 = 160000 B, pad to 160256) | samples
  float* y2 = (float*)d_ws;
  int* samples = (int*)((char*)d_ws + 160256);  // 4*8192*8 i32 = 1 MiB

  y2_kernel<<<dim3((N_HEADS * N_NODES + 3) / 4), 256, 0, stream>>>(E, y2);
  knn_kernel<<<dim3(NQ / TQ, N_HEADS), 256, 0, stream>>>(E, y2, be, samples);
  predict_kernel<<<dim3(N_BATCH), 256, 0, stream>>>(E, F, U, A, be, samples, out);
}

// Round 2
// 1537.399 us; speedup vs baseline: 2.4461x; 2.4461x over previous
//
#include <hip/hip_runtime.h>
#include <math.h>
#include <stdint.h>

#define N_HEADS 4
#define N_NODES 10000
#define NPAD 10048           /* rounded up to multiple of TN */
#define EMB 128
#define N_BATCH 4096
#define NQ (2 * N_BATCH)     /* 8192 queries: [src(4096), dst(4096)] */
#define K 8
#define TQ 64
#define TN 64
#define NTILES (NPAD / TN)   /* 157 */

typedef __attribute__((ext_vector_type(8))) __bf16 bf16x8;
typedef __attribute__((ext_vector_type(16))) float floatx16;

// ---------------------------------------------------------------------------
// helpers
// ---------------------------------------------------------------------------
__device__ __forceinline__ unsigned short f2bf(float x) {
  unsigned u = __float_as_uint(x);
  u += 0x7fff + ((u >> 16) & 1);           // round-to-nearest-even
  return (unsigned short)(u >> 16);
}
__device__ __forceinline__ float bf2f(unsigned short h) {
  return __uint_as_float(((unsigned)h) << 16);
}

// async global->LDS, 16B per lane; LDS dest = uniform base + lane*16
__device__ __forceinline__ void gload_lds16(const void* g, void* l) {
  __builtin_amdgcn_global_load_lds(
      (const __attribute__((address_space(1))) void*)g,
      (__attribute__((address_space(3))) void*)(uint32_t)(uintptr_t)l,
      16, 0, 0);
}

// sorted ascending top-8 insertion (tie-break: smaller node id)
__device__ __forceinline__ void insert8(float* bs, int* bi, float s, int node) {
  if (s < bs[K - 1] || (s == bs[K - 1] && node < bi[K - 1])) {
    #pragma unroll
    for (int k2 = K - 1; k2 >= 0; --k2) {
      bool better = (s < bs[k2]) || (s == bs[k2] && node < bi[k2]);
      if (!better) break;
      if (k2 < K - 1) { bs[k2 + 1] = bs[k2]; bi[k2 + 1] = bi[k2]; }
      bs[k2] = s; bi[k2] = node;
    }
  }
}

// ---------------------------------------------------------------------------
// Kernel P: split E into bf16 hi/lo (padded to NPAD rows) + squared norms.
// One wave per (h,n). Pad rows: zeros, y2 = 1e30 (never selected).
// ---------------------------------------------------------------------------
__global__ __launch_bounds__(256) void prep_kernel(
    const float* __restrict__ E, unsigned short* __restrict__ Ehi,
    unsigned short* __restrict__ Elo, float* __restrict__ y2g) {
  int h = blockIdx.y;
  int n = blockIdx.x * 4 + (threadIdx.x >> 6);
  int lane = threadIdx.x & 63;
  float2 x = make_float2(0.f, 0.f);
  if (n < N_NODES)
    x = *(const float2*)(E + (size_t)(h * N_NODES + n) * EMB + 2 * lane);
  unsigned short h0 = f2bf(x.x), h1 = f2bf(x.y);
  unsigned short l0 = f2bf(x.x - bf2f(h0)), l1 = f2bf(x.y - bf2f(h1));
  size_t orow = (size_t)(h * NPAD + n) * EMB;
  ((ushort2*)(Ehi + orow))[lane] = make_ushort2(h0, h1);
  ((ushort2*)(Elo + orow))[lane] = make_ushort2(l0, l1);
  float s = x.x * x.x + x.y * x.y;
  #pragma unroll
  for (int o = 32; o > 0; o >>= 1) s += __shfl_xor(s, o);
  if (lane == 0) y2g[h * NPAD + n] = (n < N_NODES) ? s : 1e30f;
}

// ---------------------------------------------------------------------------
// Kernel A: MFMA knn. Grid (NQ/TQ=128, N_HEADS). 4 waves; wave (w0,w1) owns
// the 32x32 tile at rows 32*w0, cols 32*w1. Query A-frags (hi+lo, K=128)
// live in registers; node tiles stream through LDS via global_load_lds.
// score = y2[n] - 2*dot (monotone in d2). Top-8 excluding self.
// ---------------------------------------------------------------------------
__global__ __launch_bounds__(256, 2) void knn_kernel(
    const unsigned short* __restrict__ Ehi, const unsigned short* __restrict__ Elo,
    const float* __restrict__ y2g, const int* __restrict__ be,
    int* __restrict__ samples) {
  __shared__ __align__(16) unsigned short s_nhi[TN * EMB];  // 16 KiB
  __shared__ __align__(16) unsigned short s_nlo[TN * EMB];  // 16 KiB
  __shared__ __align__(16) float s_x[TQ * TN];              // 16 KiB: scores / q-staging
  __shared__ float s_ny2[TN];

  const int h = blockIdx.y, tile = blockIdx.x, tid = threadIdx.x;
  const int wave = tid >> 6, lane = tid & 63;
  const int w0 = wave >> 1, w1 = wave & 1;
  const int lm = lane & 31, lh = lane >> 5;
  const unsigned short* EhiH = Ehi + (size_t)h * NPAD * EMB;
  const unsigned short* EloH = Elo + (size_t)h * NPAD * EMB;
  const float* y2H = y2g + h * NPAD;

  // ---- prologue: stage gathered query rows through s_x, load A-frags ----
  bf16x8 ahi[8], alo[8];
  unsigned short* s_xq = (unsigned short*)s_x;
  {
    int r = tid >> 2, cbase = (tid & 3) * 4;    // 4 chunks of 8 ushort each
    int q = be[tile * TQ + r];
    const unsigned short* src = EhiH + (size_t)q * EMB;
    #pragma unroll
    for (int c = 0; c < 4; ++c)
      *(bf16x8*)&s_xq[r * EMB + (cbase + c) * 8] =
          *(const bf16x8*)&src[(cbase + c) * 8];
    __syncthreads();
    #pragma unroll
    for (int ks = 0; ks < 8; ++ks)
      ahi[ks] = *(const bf16x8*)&s_xq[(32 * w0 + lm) * EMB + ks * 16 + lh * 8];
    __syncthreads();
    src = EloH + (size_t)q * EMB;
    #pragma unroll
    for (int c = 0; c < 4; ++c)
      *(bf16x8*)&s_xq[r * EMB + (cbase + c) * 8] =
          *(const bf16x8*)&src[(cbase + c) * 8];
    __syncthreads();
    #pragma unroll
    for (int ks = 0; ks < 8; ++ks)
      alo[ks] = *(const bf16x8*)&s_xq[(32 * w0 + lm) * EMB + ks * 16 + lh * 8];
  }

  // selection state: 4 threads per query, each owns a 16-node column chunk
  const int qsel = tid >> 2;
  const int csel = tid & 3;
  const int myq = be[tile * TQ + qsel];
  float bs[K]; int bi[K];
  #pragma unroll
  for (int k2 = 0; k2 < K; ++k2) { bs[k2] = 1e30f; bi[k2] = 0x7fffffff; }

  for (int t = 0; t < NTILES; ++t) {
    __syncthreads();  // A: prev MFMA reads done; prev score writes visible
    {   // issue async staging of node tile t (each wave: 4 KiB per buffer)
      int nb = t * TN;
      const unsigned short* gh = EhiH + (size_t)nb * EMB + wave * 2048;
      const unsigned short* gl = EloH + (size_t)nb * EMB + wave * 2048;
      unsigned short* dh = s_nhi + wave * 2048;
      unsigned short* dl = s_nlo + wave * 2048;
      #pragma unroll
      for (int it = 0; it < 4; ++it) {
        gload_lds16(gh + it * 512 + lane * 8, dh + it * 512);
        gload_lds16(gl + it * 512 + lane * 8, dl + it * 512);
      }
      if (tid < TN) s_ny2[tid] = y2H[nb + tid];
    }
    if (t > 0) {  // selection on tile t-1's scores (bank-rotated scan)
      int nbp = (t - 1) * TN;
      #pragma unroll
      for (int s = 0; s < 16; ++s) {
        int j = csel * 16 + ((s + qsel) & 15);
        float sc = s_x[qsel * TN + j];
        int node = nbp + j;
        if (node == myq || node >= N_NODES) continue;
        insert8(bs, bi, sc, node);
      }
    }
    __syncthreads();  // B: staging complete (drains vmcnt), scores consumed

    floatx16 acc = {0.f, 0.f, 0.f, 0.f, 0.f, 0.f, 0.f, 0.f,
                    0.f, 0.f, 0.f, 0.f, 0.f, 0.f, 0.f, 0.f};
    const unsigned short* bh = s_nhi + (32 * w1 + lm) * EMB + lh * 8;
    const unsigned short* bl = s_nlo + (32 * w1 + lm) * EMB + lh * 8;
    #pragma unroll
    for (int ks = 0; ks < 8; ++ks) {
      bf16x8 vbh = *(const bf16x8*)(bh + ks * 16);
      bf16x8 vbl = *(const bf16x8*)(bl + ks * 16);
      acc = __builtin_amdgcn_mfma_f32_32x32x16_bf16(alo[ks], vbh, acc, 0, 0, 0);
      acc = __builtin_amdgcn_mfma_f32_32x32x16_bf16(ahi[ks], vbl, acc, 0, 0, 0);
      acc = __builtin_amdgcn_mfma_f32_32x32x16_bf16(ahi[ks], vbh, acc, 0, 0, 0);
    }
    // scores -> s_x   (C/D layout: col=lane&31, row=(r&3)+8*(r>>2)+4*(lane>>5))
    float ny = s_ny2[32 * w1 + lm];
    #pragma unroll
    for (int r = 0; r < 16; ++r) {
      int row = (r & 3) + 8 * (r >> 2) + 4 * lh;
      s_x[(32 * w0 + row) * TN + 32 * w1 + lm] = fmaf(-2.f, acc[r], ny);
    }
  }

  // selection for the last tile
  __syncthreads();
  {
    int nbp = (NTILES - 1) * TN;
    #pragma unroll
    for (int s = 0; s < 16; ++s) {
      int j = csel * 16 + ((s + qsel) & 15);
      float sc = s_x[qsel * TN + j];
      int node = nbp + j;
      if (node == myq || node >= N_NODES) continue;
      insert8(bs, bi, sc, node);
    }
  }
  // merge the 4 per-thread lists per query
  __syncthreads();
  float* ms = (float*)s_nhi;   // 256*8*4 = 8 KiB
  int*   mi = (int*)s_nlo;
  #pragma unroll
  for (int k2 = 0; k2 < K; ++k2) { ms[tid * 8 + k2] = bs[k2]; mi[tid * 8 + k2] = bi[k2]; }
  __syncthreads();
  if (tid < TQ) {
    float fs[K]; int fi[K];
    #pragma unroll
    for (int k2 = 0; k2 < K; ++k2) { fs[k2] = 1e30f; fi[k2] = 0x7fffffff; }
    for (int s = 0; s < 32; ++s) {
      int e = (s + tid) & 31;                    // bank-rotated scan
      insert8(fs, fi, ms[tid * 32 + e], mi[tid * 32 + e]);
    }
    int gq = tile * TQ + tid;
    #pragma unroll
    for (int k2 = 0; k2 < K; ++k2)
      samples[((size_t)h * NQ + gq) * K + k2] = fi[k2];
  }
}

// ---------------------------------------------------------------------------
// Kernel B: epilogue (unchanged from round 1 — verified absmax 0.0).
// ---------------------------------------------------------------------------
__global__ __launch_bounds__(256) void predict_kernel(
    const float* __restrict__ E, const float* __restrict__ F,
    const float* __restrict__ unc, const float* __restrict__ adj,
    const int* __restrict__ be, const int* __restrict__ samples,
    float* __restrict__ out) {
  int b = blockIdx.x;
  int h = threadIdx.x >> 6;
  int lane = threadIdx.x & 63;
  __shared__ float smv[N_HEADS];

  int srcb = be[b];
  int dstb = be[N_BATCH + b];
  const float* Eh = E + (size_t)h * N_NODES * EMB;
  const float* Fh = F + (size_t)h * N_NODES * EMB;
  float2 es = *(const float2*)(Eh + (size_t)srcb * EMB + 2 * lane);
  float2 ed = *(const float2*)(Eh + (size_t)dstb * EMB + 2 * lane);
  float2 fs = *(const float2*)(Fh + (size_t)srcb * EMB + 2 * lane);
  float2 fd = *(const float2*)(Fh + (size_t)dstb * EMB + 2 * lane);
  float u = unc[0];

  float logit[16], dist[16];
  #pragma unroll
  for (int j = 0; j < 16; ++j) {
    bool isrc = (j < 8);
    int qrow = isrc ? b : (N_BATCH + b);
    int s = samples[((size_t)h * NQ + qrow) * K + (j & 7)];
    float2 ev = *(const float2*)(Eh + (size_t)s * EMB + 2 * lane);
    float2 bb = isrc ? es : ed;
    float2 g = isrc ? fd : fs;
    float dx = bb.x - ev.x, dy = bb.y - ev.y;
    float dot = dx * g.x + dy * g.y;
    float nrm = dx * dx + dy * dy;
    #pragma unroll
    for (int o = 32; o > 0; o >>= 1) {
      dot += __shfl_xor(dot, o);
      nrm += __shfl_xor(nrm, o);
    }
    float a = isrc ? adj[(size_t)s * N_NODES + dstb]
                   : adj[(size_t)srcb * N_NODES + s];
    logit[j] = dot + u * (2.0f * a - 1.0f);
    dist[j] = sqrtf(nrm);
  }

  float m = 0.0f;  // sentinel: 1 - 1.0 = 0
  #pragma unroll
  for (int j = 0; j < 16; ++j) m = fmaxf(m, 1.0f - dist[j]);
  float Z = 8.0f * expf(-m);
  float num = 0.0f;
  #pragma unroll
  for (int j = 0; j < 16; ++j) {
    float e = expf(1.0f - dist[j] - m);
    Z += e;
    num += logit[j] * e;
  }
  if (lane == 0) smv[h] = num / Z;
  __syncthreads();
  if (threadIdx.x == 0) {
    float t = 0.25f * (smv[0] + smv[1] + smv[2] + smv[3]);
    out[b] = 1.0f / (1.0f + expf(-t));
  }
}

// ---------------------------------------------------------------------------
extern "C" void kernel_launch(void* const* d_in, const int* in_sizes, int n_in,
                              void* d_out, int out_size, void* d_ws,
                              size_t ws_size, hipStream_t stream) {
  const float* E = (const float*)d_in[0];
  const float* F = (const float*)d_in[1];
  const float* U = (const float*)d_in[2];
  const float* A = (const float*)d_in[3];
  const int* be = (const int*)d_in[4];
  float* out = (float*)d_out;

  // ws layout (256B-aligned): Ehi | Elo | y2g | samples  (~21.8 MB total)
  char* w = (char*)d_ws;
  unsigned short* Ehi = (unsigned short*)(w);
  unsigned short* Elo = (unsigned short*)(w + 10289152);
  float* y2g = (float*)(w + 2 * 10289152);
  int* samples = (int*)(w + 2 * 10289152 + 160768);

  prep_kernel<<<dim3(NPAD / 4, N_HEADS), 256, 0, stream>>>(E, Ehi, Elo, y2g);
  knn_kernel<<<dim3(NQ / TQ, N_HEADS), 256, 0, stream>>>(Ehi, Elo, y2g, be, samples);
  predict_kernel<<<dim3(N_BATCH), 256, 0, stream>>>(E, F, U, A, be, samples, out);
}

// Round 3
// 1156.851 us; speedup vs baseline: 3.2507x; 1.3290x over previous
//
#include <hip/hip_runtime.h>
#include <math.h>
#include <stdint.h>

#define N_HEADS 4
#define N_NODES 10000
#define NPAD 10048           /* rounded up to multiple of TN */
#define EMB 128
#define N_BATCH 4096
#define NQ (2 * N_BATCH)     /* 8192 queries: [src(4096), dst(4096)] */
#define K 8
#define TQ 64
#define TN 64
#define NTILES (NPAD / TN)   /* 157 */

typedef __attribute__((ext_vector_type(8))) __bf16 bf16x8;
typedef __attribute__((ext_vector_type(16))) float floatx16;

// ---------------------------------------------------------------------------
// helpers
// ---------------------------------------------------------------------------
__device__ __forceinline__ unsigned short f2bf(float x) {
  unsigned u = __float_as_uint(x);
  u += 0x7fff + ((u >> 16) & 1);           // round-to-nearest-even
  return (unsigned short)(u >> 16);
}
__device__ __forceinline__ float bf2f(unsigned short h) {
  return __uint_as_float(((unsigned)h) << 16);
}

// async global->LDS, 16B per lane; LDS dest = uniform base + lane*16
__device__ __forceinline__ void gload_lds16(const void* g, void* l) {
  __builtin_amdgcn_global_load_lds(
      (const __attribute__((address_space(1))) void*)g,
      (__attribute__((address_space(3))) void*)(uint32_t)(uintptr_t)l,
      16, 0, 0);
}

// sorted ascending top-8 insertion (tie-break: smaller node id)
__device__ __forceinline__ void insert8(float* bs, int* bi, float s, int node) {
  if (s < bs[K - 1] || (s == bs[K - 1] && node < bi[K - 1])) {
    #pragma unroll
    for (int k2 = K - 1; k2 >= 0; --k2) {
      bool better = (s < bs[k2]) || (s == bs[k2] && node < bi[k2]);
      if (!better) break;
      if (k2 < K - 1) { bs[k2 + 1] = bs[k2]; bi[k2 + 1] = bi[k2]; }
      bs[k2] = s; bi[k2] = node;
    }
  }
}

// ---------------------------------------------------------------------------
// Kernel P: split E into bf16 hi/lo (padded to NPAD rows) + squared norms.
// One wave per (h,n). Pad rows: zeros, y2 = 1e30 (never selected).
// ---------------------------------------------------------------------------
__global__ __launch_bounds__(256) void prep_kernel(
    const float* __restrict__ E, unsigned short* __restrict__ Ehi,
    unsigned short* __restrict__ Elo, float* __restrict__ y2g) {
  int h = blockIdx.y;
  int n = blockIdx.x * 4 + (threadIdx.x >> 6);
  int lane = threadIdx.x & 63;
  float2 x = make_float2(0.f, 0.f);
  if (n < N_NODES)
    x = *(const float2*)(E + (size_t)(h * N_NODES + n) * EMB + 2 * lane);
  unsigned short h0 = f2bf(x.x), h1 = f2bf(x.y);
  unsigned short l0 = f2bf(x.x - bf2f(h0)), l1 = f2bf(x.y - bf2f(h1));
  size_t orow = (size_t)(h * NPAD + n) * EMB;
  ((ushort2*)(Ehi + orow))[lane] = make_ushort2(h0, h1);
  ((ushort2*)(Elo + orow))[lane] = make_ushort2(l0, l1);
  float s = x.x * x.x + x.y * x.y;
  #pragma unroll
  for (int o = 32; o > 0; o >>= 1) s += __shfl_xor(s, o);
  if (lane == 0) y2g[h * NPAD + n] = (n < N_NODES) ? s : 1e30f;
}

// ---------------------------------------------------------------------------
// Kernel A: MFMA knn. Grid (NQ/TQ=128, N_HEADS). 4 waves; wave (w0,w1) owns
// the 32x32 tile at rows 32*w0, cols 32*w1. Query A-frags (hi+lo, K=128)
// live in registers; node tiles stream through LDS via global_load_lds.
//
// LDS tiles use an XOR-16 chunk swizzle: row r's 16B chunk c is stored at
// physical chunk c^(r&15). The DMA can't scatter on the LDS side, so the
// permutation is applied to the per-lane GLOBAL source address instead
// (still coalesced: a permutation within each 256B row). B-fragment
// ds_read_b128 then hits all 16 chunk positions across 16 lanes -> 2-way
// bank aliasing only (free per m136), vs ~16-way before.
//
// score = y2[n] - 2*dot (monotone in d2). Top-8 excluding self.
// ---------------------------------------------------------------------------
__global__ __launch_bounds__(256, 2) void knn_kernel(
    const unsigned short* __restrict__ Ehi, const unsigned short* __restrict__ Elo,
    const float* __restrict__ y2g, const int* __restrict__ be,
    int* __restrict__ samples) {
  __shared__ __align__(16) unsigned short s_nhi[TN * EMB];  // 16 KiB
  __shared__ __align__(16) unsigned short s_nlo[TN * EMB];  // 16 KiB
  __shared__ __align__(16) float s_x[TQ * TN];              // 16 KiB: scores / q-staging
  __shared__ float s_ny2[TN];

  const int h = blockIdx.y, tile = blockIdx.x, tid = threadIdx.x;
  const int wave = tid >> 6, lane = tid & 63;
  const int w0 = wave >> 1, w1 = wave & 1;
  const int lm = lane & 31, lh = lane >> 5;
  const unsigned short* EhiH = Ehi + (size_t)h * NPAD * EMB;
  const unsigned short* EloH = Elo + (size_t)h * NPAD * EMB;
  const float* y2H = y2g + h * NPAD;

  // ---- prologue: stage gathered query rows through s_x (swizzled), load A ----
  bf16x8 ahi[8], alo[8];
  unsigned short* s_xq = (unsigned short*)s_x;
  {
    int r = tid >> 2, cbase = (tid & 3) * 4;    // 4 chunks of 8 ushort each
    int rx15 = r & 15;
    int q = be[tile * TQ + r];
    const int arow = 32 * w0 + lm;
    const int arx = arow & 15;
    const unsigned short* src = EhiH + (size_t)q * EMB;
    #pragma unroll
    for (int c = 0; c < 4; ++c) {
      int lc = cbase + c;
      *(bf16x8*)&s_xq[r * EMB + (lc ^ rx15) * 8] = *(const bf16x8*)&src[lc * 8];
    }
    __syncthreads();
    #pragma unroll
    for (int ks = 0; ks < 8; ++ks)
      ahi[ks] = *(const bf16x8*)&s_xq[arow * EMB + (((ks * 2 + lh) ^ arx)) * 8];
    __syncthreads();
    src = EloH + (size_t)q * EMB;
    #pragma unroll
    for (int c = 0; c < 4; ++c) {
      int lc = cbase + c;
      *(bf16x8*)&s_xq[r * EMB + (lc ^ rx15) * 8] = *(const bf16x8*)&src[lc * 8];
    }
    __syncthreads();
    #pragma unroll
    for (int ks = 0; ks < 8; ++ks)
      alo[ks] = *(const bf16x8*)&s_xq[arow * EMB + (((ks * 2 + lh) ^ arx)) * 8];
  }

  // selection state: 4 threads per query, each owns a 16-node column chunk
  const int qsel = tid >> 2;
  const int csel = tid & 3;
  const int myq = be[tile * TQ + qsel];
  float bs[K]; int bi[K];
  #pragma unroll
  for (int k2 = 0; k2 < K; ++k2) { bs[k2] = 1e30f; bi[k2] = 0x7fffffff; }

  for (int t = 0; t < NTILES; ++t) {
    __syncthreads();  // A: prev MFMA reads done; prev score writes visible
    {   // async staging of node tile t; source address carries the swizzle
      int nb = t * TN;
      #pragma unroll
      for (int it = 0; it < 4; ++it) {
        int q = wave * 256 + it * 64 + lane;   // chunk-linear index 0..1023
        int r = q >> 4;
        int c = (q ^ r) & 15;
        const unsigned short* sh = EhiH + (size_t)(nb + r) * EMB + c * 8;
        const unsigned short* sl = EloH + (size_t)(nb + r) * EMB + c * 8;
        gload_lds16(sh, s_nhi + wave * 2048 + it * 512);
        gload_lds16(sl, s_nlo + wave * 2048 + it * 512);
      }
      if (tid < TN) s_ny2[tid] = y2H[nb + tid];
    }
    if (t > 0) {  // selection on tile t-1's scores (bank-rotated scan)
      int nbp = (t - 1) * TN;
      #pragma unroll
      for (int s = 0; s < 16; ++s) {
        int j = csel * 16 + ((s + qsel) & 15);
        float sc = s_x[qsel * TN + j];
        int node = nbp + j;
        if (node == myq || node >= N_NODES) continue;
        insert8(bs, bi, sc, node);
      }
    }
    __syncthreads();  // B: staging complete (drains vmcnt), scores consumed

    floatx16 acc = {0.f, 0.f, 0.f, 0.f, 0.f, 0.f, 0.f, 0.f,
                    0.f, 0.f, 0.f, 0.f, 0.f, 0.f, 0.f, 0.f};
    const int brow = 32 * w1 + lm;
    const int brx = brow & 15;
    const unsigned short* nh = s_nhi + brow * EMB;
    const unsigned short* nl = s_nlo + brow * EMB;
    #pragma unroll
    for (int ks = 0; ks < 8; ++ks) {
      int pc = ((ks * 2 + lh) ^ brx) * 8;
      bf16x8 vbh = *(const bf16x8*)(nh + pc);
      bf16x8 vbl = *(const bf16x8*)(nl + pc);
      acc = __builtin_amdgcn_mfma_f32_32x32x16_bf16(alo[ks], vbh, acc, 0, 0, 0);
      acc = __builtin_amdgcn_mfma_f32_32x32x16_bf16(ahi[ks], vbl, acc, 0, 0, 0);
      acc = __builtin_amdgcn_mfma_f32_32x32x16_bf16(ahi[ks], vbh, acc, 0, 0, 0);
    }
    // scores -> s_x   (C/D layout: col=lane&31, row=(r&3)+8*(r>>2)+4*(lane>>5))
    float ny = s_ny2[brow & 31];
    #pragma unroll
    for (int r = 0; r < 16; ++r) {
      int row = (r & 3) + 8 * (r >> 2) + 4 * lh;
      s_x[(32 * w0 + row) * TN + 32 * w1 + lm] = fmaf(-2.f, acc[r], ny);
    }
  }

  // selection for the last tile
  __syncthreads();
  {
    int nbp = (NTILES - 1) * TN;
    #pragma unroll
    for (int s = 0; s < 16; ++s) {
      int j = csel * 16 + ((s + qsel) & 15);
      float sc = s_x[qsel * TN + j];
      int node = nbp + j;
      if (node == myq || node >= N_NODES) continue;
      insert8(bs, bi, sc, node);
    }
  }
  // merge the 4 per-thread lists per query
  __syncthreads();
  float* ms = (float*)s_nhi;   // 256*8*4 = 8 KiB
  int*   mi = (int*)s_nlo;
  #pragma unroll
  for (int k2 = 0; k2 < K; ++k2) { ms[tid * 8 + k2] = bs[k2]; mi[tid * 8 + k2] = bi[k2]; }
  __syncthreads();
  if (tid < TQ) {
    float fs[K]; int fi[K];
    #pragma unroll
    for (int k2 = 0; k2 < K; ++k2) { fs[k2] = 1e30f; fi[k2] = 0x7fffffff; }
    for (int s = 0; s < 32; ++s) {
      int e = (s + tid) & 31;                    // bank-rotated scan
      insert8(fs, fi, ms[tid * 32 + e], mi[tid * 32 + e]);
    }
    int gq = tile * TQ + tid;
    #pragma unroll
    for (int k2 = 0; k2 < K; ++k2)
      samples[((size_t)h * NQ + gq) * K + k2] = fi[k2];
  }
}

// ---------------------------------------------------------------------------
// Kernel B: epilogue (unchanged — verified absmax 0.0).
// ---------------------------------------------------------------------------
__global__ __launch_bounds__(256) void predict_kernel(
    const float* __restrict__ E, const float* __restrict__ F,
    const float* __restrict__ unc, const float* __restrict__ adj,
    const int* __restrict__ be, const int* __restrict__ samples,
    float* __restrict__ out) {
  int b = blockIdx.x;
  int h = threadIdx.x >> 6;
  int lane = threadIdx.x & 63;
  __shared__ float smv[N_HEADS];

  int srcb = be[b];
  int dstb = be[N_BATCH + b];
  const float* Eh = E + (size_t)h * N_NODES * EMB;
  const float* Fh = F + (size_t)h * N_NODES * EMB;
  float2 es = *(const float2*)(Eh + (size_t)srcb * EMB + 2 * lane);
  float2 ed = *(const float2*)(Eh + (size_t)dstb * EMB + 2 * lane);
  float2 fs = *(const float2*)(Fh + (size_t)srcb * EMB + 2 * lane);
  float2 fd = *(const float2*)(Fh + (size_t)dstb * EMB + 2 * lane);
  float u = unc[0];

  float logit[16], dist[16];
  #pragma unroll
  for (int j = 0; j < 16; ++j) {
    bool isrc = (j < 8);
    int qrow = isrc ? b : (N_BATCH + b);
    int s = samples[((size_t)h * NQ + qrow) * K + (j & 7)];
    float2 ev = *(const float2*)(Eh + (size_t)s * EMB + 2 * lane);
    float2 bb = isrc ? es : ed;
    float2 g = isrc ? fd : fs;
    float dx = bb.x - ev.x, dy = bb.y - ev.y;
    float dot = dx * g.x + dy * g.y;
    float nrm = dx * dx + dy * dy;
    #pragma unroll
    for (int o = 32; o > 0; o >>= 1) {
      dot += __shfl_xor(dot, o);
      nrm += __shfl_xor(nrm, o);
    }
    float a = isrc ? adj[(size_t)s * N_NODES + dstb]
                   : adj[(size_t)srcb * N_NODES + s];
    logit[j] = dot + u * (2.0f * a - 1.0f);
    dist[j] = sqrtf(nrm);
  }

  float m = 0.0f;  // sentinel: 1 - 1.0 = 0
  #pragma unroll
  for (int j = 0; j < 16; ++j) m = fmaxf(m, 1.0f - dist[j]);
  float Z = 8.0f * expf(-m);
  float num = 0.0f;
  #pragma unroll
  for (int j = 0; j < 16; ++j) {
    float e = expf(1.0f - dist[j] - m);
    Z += e;
    num += logit[j] * e;
  }
  if (lane == 0) smv[h] = num / Z;
  __syncthreads();
  if (threadIdx.x == 0) {
    float t = 0.25f * (smv[0] + smv[1] + smv[2] + smv[3]);
    out[b] = 1.0f / (1.0f + expf(-t));
  }
}

// ---------------------------------------------------------------------------
extern "C" void kernel_launch(void* const* d_in, const int* in_sizes, int n_in,
                              void* d_out, int out_size, void* d_ws,
                              size_t ws_size, hipStream_t stream) {
  const float* E = (const float*)d_in[0];
  const float* F = (const float*)d_in[1];
  const float* U = (const float*)d_in[2];
  const float* A = (const float*)d_in[3];
  const int* be = (const int*)d_in[4];
  float* out = (float*)d_out;

  // ws layout (256B-aligned): Ehi | Elo | y2g | samples  (~21.8 MB total)
  char* w = (char*)d_ws;
  unsigned short* Ehi = (unsigned short*)(w);
  unsigned short* Elo = (unsigned short*)(w + 10289152);
  float* y2g = (float*)(w + 2 * 10289152);
  int* samples = (int*)(w + 2 * 10289152 + 160768);

  prep_kernel<<<dim3(NPAD / 4, N_HEADS), 256, 0, stream>>>(E, Ehi, Elo, y2g);
  knn_kernel<<<dim3(NQ / TQ, N_HEADS), 256, 0, stream>>>(Ehi, Elo, y2g, be, samples);
  predict_kernel<<<dim3(N_BATCH), 256, 0, stream>>>(E, F, U, A, be, samples, out);
}